// Round 1
// baseline (265.978 us; speedup 1.0000x reference)
//
#include <hip/hip_runtime.h>

typedef __attribute__((ext_vector_type(8))) _Float16 half8;
typedef __attribute__((ext_vector_type(4))) _Float16 half4;
typedef __attribute__((ext_vector_type(4))) float f32x4;

#define MFMA16(a, b, c) __builtin_amdgcn_mfma_f32_16x16x32_f16((a), (b), (c), 0, 0, 0)

// ---------------------------------------------------------------------------
// Constants for this problem instance
// ---------------------------------------------------------------------------
// B=32, S=512, Dm=768, H=12, D_HEAD=64, M = B*S = 16384
// probs = (scores*0.125 + 5)^2 ; probs /= (rowsum + 1e-10) ; probs *= mask
// ctx = probs @ V
// Folded: ctx = (sum_k w_k * mask_k * v_k) / (sum_k w_k + 1e-10)

// ---------------------------------------------------------------------------
// Kernel 1: transpose + cast weights: Wt[n][k] = (f16) W[k][n], 768x768 x3
// ---------------------------------------------------------------------------
__global__ __launch_bounds__(256) void wcast_kernel(
    const float* __restrict__ W0, const float* __restrict__ W1,
    const float* __restrict__ W2,
    _Float16* __restrict__ T0, _Float16* __restrict__ T1,
    _Float16* __restrict__ T2)
{
    int z = blockIdx.z;
    const float* W = (z == 0) ? W0 : (z == 1) ? W1 : W2;
    _Float16* T = (z == 0) ? T0 : (z == 1) ? T1 : T2;
    __shared__ float tile[32][33];
    int n0 = blockIdx.x * 32, k0 = blockIdx.y * 32;
    int tx = threadIdx.x & 31, ty = threadIdx.x >> 5;  // ty in 0..7
#pragma unroll
    for (int r = 0; r < 4; ++r)
        tile[ty + 8 * r][tx] = W[(size_t)(k0 + ty + 8 * r) * 768 + n0 + tx];
    __syncthreads();
#pragma unroll
    for (int r = 0; r < 4; ++r)
        T[(size_t)(n0 + ty + 8 * r) * 768 + k0 + tx] =
            (_Float16)tile[tx][ty + 8 * r];
}

// ---------------------------------------------------------------------------
// Kernel 2: QKV projection GEMM. C[M=16384, N=768] = X f32 @ W + bias.
// z = 0/1/2 -> Q/K/V. Q,K stored f16 [B,H,S,64]; V stored transposed [B,H,64,S].
// Tile 128x128, BK=32, 4 waves each 64x64 (4x4 fragments of 16x16x32 MFMA).
// LDS rows padded to 40 halves (80B) -> 2-way bank aliasing only (free).
// ---------------------------------------------------------------------------
__global__ __launch_bounds__(256) void qkv_gemm(
    const float* __restrict__ X,
    const _Float16* __restrict__ W0, const _Float16* __restrict__ W1,
    const _Float16* __restrict__ W2,
    const float* __restrict__ b0, const float* __restrict__ b1,
    const float* __restrict__ b2,
    _Float16* __restrict__ Qo, _Float16* __restrict__ Ko,
    _Float16* __restrict__ Vo)
{
    int z = blockIdx.z;
    const _Float16* Wt = (z == 0) ? W0 : (z == 1) ? W1 : W2;
    const float* bias = (z == 0) ? b0 : (z == 1) ? b1 : b2;
    _Float16* outp = (z == 0) ? Qo : (z == 1) ? Ko : Vo;

    int m0 = blockIdx.x * 128;
    int n0 = blockIdx.y * 128;

    __shared__ _Float16 As[128 * 40];  // [row][k], stride 40 halves = 80B
    __shared__ _Float16 Bs[128 * 40];  // [n][k]

    int t = threadIdx.x;
    int wave = t >> 6, lane = t & 63, quad = lane >> 4, l16 = lane & 15;
    int wm = (wave & 1) * 64, wn = (wave >> 1) * 64;
    int arow = t >> 1, ahalf = t & 1;  // staging: 2 threads per 128-row, 16 elems each

    f32x4 acc[4][4] = {};

    for (int k0 = 0; k0 < 768; k0 += 32) {
        // ---- stage A tile: X[m0+arow][k0 + ahalf*16 .. +15], f32 -> f16
        {
            const float* xp = X + (size_t)(m0 + arow) * 768 + k0 + ahalf * 16;
            float4 x0 = ((const float4*)xp)[0];
            float4 x1 = ((const float4*)xp)[1];
            float4 x2 = ((const float4*)xp)[2];
            float4 x3 = ((const float4*)xp)[3];
            half8 h0, h1;
            h0[0] = (_Float16)x0.x; h0[1] = (_Float16)x0.y;
            h0[2] = (_Float16)x0.z; h0[3] = (_Float16)x0.w;
            h0[4] = (_Float16)x1.x; h0[5] = (_Float16)x1.y;
            h0[6] = (_Float16)x1.z; h0[7] = (_Float16)x1.w;
            h1[0] = (_Float16)x2.x; h1[1] = (_Float16)x2.y;
            h1[2] = (_Float16)x2.z; h1[3] = (_Float16)x2.w;
            h1[4] = (_Float16)x3.x; h1[5] = (_Float16)x3.y;
            h1[6] = (_Float16)x3.z; h1[7] = (_Float16)x3.w;
            *(half8*)&As[arow * 40 + ahalf * 16] = h0;
            *(half8*)&As[arow * 40 + ahalf * 16 + 8] = h1;
        }
        // ---- stage B tile: Wt[n0+arow][k0 + ahalf*16 .. +15] (already f16)
        {
            const _Float16* wp = Wt + (size_t)(n0 + arow) * 768 + k0 + ahalf * 16;
            half8 w0v = ((const half8*)wp)[0];
            half8 w1v = ((const half8*)wp)[1];
            *(half8*)&Bs[arow * 40 + ahalf * 16] = w0v;
            *(half8*)&Bs[arow * 40 + ahalf * 16 + 8] = w1v;
        }
        __syncthreads();

        half8 af[4], bfr[4];
#pragma unroll
        for (int i = 0; i < 4; ++i)
            af[i] = *(const half8*)&As[(wm + i * 16 + l16) * 40 + quad * 8];
#pragma unroll
        for (int j = 0; j < 4; ++j)
            bfr[j] = *(const half8*)&Bs[(wn + j * 16 + l16) * 40 + quad * 8];
#pragma unroll
        for (int i = 0; i < 4; ++i)
#pragma unroll
            for (int j = 0; j < 4; ++j)
                acc[i][j] = MFMA16(af[i], bfr[j], acc[i][j]);
        __syncthreads();
    }

    // ---- epilogue: C row = wm + i*16 + quad*4 + reg ; col = wn + j*16 + l16
#pragma unroll
    for (int j = 0; j < 4; ++j) {
        int n = n0 + wn + j * 16 + l16;
        float bv = bias[n];
        int hh = n >> 6, d = n & 63;
#pragma unroll
        for (int i = 0; i < 4; ++i) {
            int mbase = m0 + wm + i * 16 + quad * 4;
            if (z < 2) {
                // [B,H,S,64]
#pragma unroll
                for (int r = 0; r < 4; ++r) {
                    int m = mbase + r;
                    int bb = m >> 9, s = m & 511;
                    size_t off = (((size_t)(bb * 12 + hh)) * 512 + s) * 64 + d;
                    outp[off] = (_Float16)(acc[i][j][r] + bv);
                }
            } else {
                // V transposed: [B,H,64,S]; regs = consecutive tokens -> 8B store
                int bb = mbase >> 9, s = mbase & 511;
                half4 pk;
#pragma unroll
                for (int r = 0; r < 4; ++r)
                    pk[r] = (_Float16)(acc[i][j][r] + bv);
                size_t off = (((size_t)(bb * 12 + hh)) * 64 + d) * 512 + s;
                *(half4*)&outp[off] = pk;
            }
        }
    }
}

// ---------------------------------------------------------------------------
// Kernel 3: power-law attention. Block = (qtile, h, b); 4 waves x 32 queries.
// K-loop over 8 tiles of 64 keys:
//   scores = Q Kt (MFMA) -> w = (0.125 s + 5)^2 -> rowsum += w (unmasked)
//   P = f16(w * mask) via LDS round trip (C-layout -> A-layout)
//   ctx += P @ V (MFMA, B operand from V^T tile)
// Epilogue: ctx / (rowsum + 1e-10) -> out f32 [B,S,768]
// ---------------------------------------------------------------------------
__global__ __launch_bounds__(256) void attn_kernel(
    const _Float16* __restrict__ Q, const _Float16* __restrict__ K,
    const _Float16* __restrict__ Vt, const float* __restrict__ mask,
    float* __restrict__ out)
{
    __shared__ _Float16 Ks[64 * 72];      // [key][d], stride 72 halves = 144B
    __shared__ _Float16 Vs[64 * 72];      // [d][key]
    __shared__ _Float16 Ps[4][32 * 72];   // per-wave P buffer [q][key]
    __shared__ float Ms[64];

    int t = threadIdx.x;
    int wave = t >> 6, lane = t & 63, quad = lane >> 4, l16 = lane & 15;
    int qt = blockIdx.x, h = blockIdx.y, b = blockIdx.z;
    size_t bh = (size_t)b * 12 + h;
    const _Float16* Qp = Q + bh * (512 * 64);
    const _Float16* Kp = K + bh * (512 * 64);
    const _Float16* Vp = Vt + bh * (64 * 512);
    int qbase = qt * 128 + wave * 32;

    // Q fragments held in registers for the whole block
    half8 qf[2][2];
#pragma unroll
    for (int i = 0; i < 2; ++i)
#pragma unroll
        for (int ks = 0; ks < 2; ++ks)
            qf[i][ks] = *(const half8*)(Qp + (size_t)(qbase + i * 16 + l16) * 64 +
                                        ks * 32 + quad * 8);

    f32x4 ctx[2][4] = {};
    float rs[2][4] = {};  // per-lane partial row sums (cols == l16 mod 16)

    int skey = t >> 2, spart = t & 3;  // staging: 4 threads per 64-elem row

    for (int kt = 0; kt < 8; ++kt) {
        int k0 = kt * 64;
        __syncthreads();
        // ---- stage K tile [64 keys][64 d] and V^T tile [64 d][64 keys]
        {
            const half8* kg = (const half8*)(Kp + (size_t)(k0 + skey) * 64 + spart * 16);
            half8 a0 = kg[0], a1 = kg[1];
            *(half8*)&Ks[skey * 72 + spart * 16] = a0;
            *(half8*)&Ks[skey * 72 + spart * 16 + 8] = a1;
            const half8* vg = (const half8*)(Vp + (size_t)skey * 512 + k0 + spart * 16);
            half8 v0 = vg[0], v1 = vg[1];
            *(half8*)&Vs[skey * 72 + spart * 16] = v0;
            *(half8*)&Vs[skey * 72 + spart * 16 + 8] = v1;
            if (t < 64) Ms[t] = mask[(size_t)b * 512 + k0 + t];
        }
        __syncthreads();

        // ---- scores + power law + P write
#pragma unroll
        for (int i = 0; i < 2; ++i) {
#pragma unroll
            for (int n = 0; n < 4; ++n) {
                f32x4 sc = {0.f, 0.f, 0.f, 0.f};
#pragma unroll
                for (int ks = 0; ks < 2; ++ks) {
                    half8 kf = *(const half8*)&Ks[(n * 16 + l16) * 72 + ks * 32 + quad * 8];
                    sc = MFMA16(qf[i][ks], kf, sc);
                }
                float mk = Ms[n * 16 + l16];
#pragma unroll
                for (int r = 0; r < 4; ++r) {
                    float s = sc[r] * 0.125f + 5.0f;
                    float w = s * s;
                    rs[i][r] += w;  // unmasked rowsum (mask applied post-normalize)
                    Ps[wave][(i * 16 + quad * 4 + r) * 72 + n * 16 + l16] =
                        (_Float16)(w * mk);
                }
            }
        }
        __syncthreads();

        // ---- PV: ctx[q][d] += P[q][key] * V[key][d]
#pragma unroll
        for (int i = 0; i < 2; ++i) {
#pragma unroll
            for (int ks = 0; ks < 2; ++ks) {
                half8 pf = *(const half8*)&Ps[wave][(i * 16 + l16) * 72 + ks * 32 + quad * 8];
#pragma unroll
                for (int n = 0; n < 4; ++n) {
                    half8 vf = *(const half8*)&Vs[(n * 16 + l16) * 72 + ks * 32 + quad * 8];
                    ctx[i][n] = MFMA16(pf, vf, ctx[i][n]);
                }
            }
        }
    }

    // ---- rowsum butterfly across the 16 lanes of each quad, then normalize
#pragma unroll
    for (int i = 0; i < 2; ++i)
#pragma unroll
        for (int r = 0; r < 4; ++r) {
            float v = rs[i][r];
            v += __shfl_xor(v, 1, 64);
            v += __shfl_xor(v, 2, 64);
            v += __shfl_xor(v, 4, 64);
            v += __shfl_xor(v, 8, 64);
            rs[i][r] = 1.0f / (v + 1e-10f);
        }
#pragma unroll
    for (int i = 0; i < 2; ++i)
#pragma unroll
        for (int n = 0; n < 4; ++n)
#pragma unroll
            for (int r = 0; r < 4; ++r) {
                int q = qbase + i * 16 + quad * 4 + r;
                int d = n * 16 + l16;
                out[((size_t)b * 512 + q) * 768 + h * 64 + d] =
                    ctx[i][n][r] * rs[i][r];
            }
}

// ---------------------------------------------------------------------------
extern "C" void kernel_launch(void* const* d_in, const int* in_sizes, int n_in,
                              void* d_out, int out_size, void* d_ws, size_t ws_size,
                              hipStream_t stream)
{
    const float* hs   = (const float*)d_in[0];
    const float* mask = (const float*)d_in[1];
    const float* Wq   = (const float*)d_in[2];
    const float* bq   = (const float*)d_in[3];
    const float* Wk   = (const float*)d_in[4];
    const float* bk   = (const float*)d_in[5];
    const float* Wv   = (const float*)d_in[6];
    const float* bv   = (const float*)d_in[7];
    float* out = (float*)d_out;

    char* ws = (char*)d_ws;
    _Float16* Wtq = (_Float16*)ws;            // 768*768 halves each
    _Float16* Wtk = Wtq + 768 * 768;
    _Float16* Wtv = Wtk + 768 * 768;
    _Float16* Qb  = Wtv + 768 * 768;          // 16384*768 halves each
    _Float16* Kb  = Qb + 16384 * 768;
    _Float16* Vb  = Kb + 16384 * 768;
    // total workspace use: (3*589824 + 3*12582912) * 2 bytes = ~79 MB

    wcast_kernel<<<dim3(24, 24, 3), 256, 0, stream>>>(Wq, Wk, Wv, Wtq, Wtk, Wtv);
    qkv_gemm<<<dim3(128, 6, 3), 256, 0, stream>>>(hs, Wtq, Wtk, Wtv,
                                                  bq, bk, bv, Qb, Kb, Vb);
    attn_kernel<<<dim3(4, 12, 32), 256, 0, stream>>>(Qb, Kb, Vb, mask, out);
}